// Round 6
// baseline (189.635 us; speedup 1.0000x reference)
//
#include <hip/hip_runtime.h>
#include <stdint.h>

#define DEV __device__ __forceinline__

typedef unsigned short u16;
typedef unsigned int u32;
typedef short bh8 __attribute__((ext_vector_type(8)));
typedef float f32x4 __attribute__((ext_vector_type(4)));

// ---------- bf16 helpers ----------
DEV float bf2f(u16 v){ return __uint_as_float(((u32)v)<<16); }
DEV u16 f2bf(float f){
    u32 x = __float_as_uint(f);
    x += 0x7fffu + ((x>>16)&1u);
    return (u16)(x>>16);
}
DEV void cvt8(int4 r, float* f){
    u32 a=(u32)r.x, b=(u32)r.y, c=(u32)r.z, d=(u32)r.w;
    f[0]=__uint_as_float(a<<16); f[1]=__uint_as_float(a&0xffff0000u);
    f[2]=__uint_as_float(b<<16); f[3]=__uint_as_float(b&0xffff0000u);
    f[4]=__uint_as_float(c<<16); f[5]=__uint_as_float(c&0xffff0000u);
    f[6]=__uint_as_float(d<<16); f[7]=__uint_as_float(d&0xffff0000u);
}
DEV int2 pk4(float a, float b, float c, float d){
    int2 r;
    r.x = (int)((u32)f2bf(a) | ((u32)f2bf(b)<<16));
    r.y = (int)((u32)f2bf(c) | ((u32)f2bf(d)<<16));
    return r;
}
DEV bh8 ld_frag(const u16* p){
    int4 v = *(const int4*)p;
    union{ int4 i; bh8 h; } u; u.i = v; return u.h;
}
// dual-dtype param load (bf16 or f32 source)
DEV float ldp(const void* p, int i, bool bf){
    return bf ? bf2f(((const u16*)p)[i]) : ((const float*)p)[i];
}
#define MFMA __builtin_amdgcn_mfma_f32_16x16x32_bf16

// Problem constants: BSZ=1, S=256, C=128, H=4, D=32, F=64.

// Param block layout (elements, bf16) inside workspace:
#define P_LNW 0
#define P_LNB 128
#define P_QW  256
#define P_QB  16640
#define P_KW  16768
#define P_KB  33152
#define P_VW  33280
#define P_VB  49664
#define P_QFW 49792
#define P_QFB 50816
#define P_KFW 50848
#define P_KFB 51872
#define P_GW  51904
#define P_GB  68288
#define P_OW  68416
#define P_OB  84800
#define P_TOT 84928
// combined feature-map weights (appended):
#define P_CQW 84928    // [h][j][c] 4*32*128
#define P_CQB 101312   // [h][j]    4*32
#define P_CKW 101440
#define P_CKB 117824

#define NCONV 332      // blocks for the convert part (332*256 >= P_TOT)

// ---------------- dtype detect: flag=1 if inputs are bf16, 0 if f32 ----------------
__global__ void detect_kernel(const u32* __restrict__ z, u32* __restrict__ flag){
    int tid = threadIdx.x;
    u32 w = z[(size_t)tid*997];
    u32 b0 = w & 0xFFFFu;
    int e = (int)((b0>>7)&0xFF);
    int good = (e>=96 && e<=150) ? 1 : 0;
    __shared__ int red[4];
    #pragma unroll
    for(int o=1;o<64;o<<=1) good += __shfl_xor(good,o,64);
    if((tid&63)==0) red[tid>>6]=good;
    __syncthreads();
    if(tid==0) *flag = ((red[0]+red[1]+red[2]+red[3]) > 192) ? 1u : 0u;
}

// ---------------- params: convert to bf16 block + build combined q/k feature weights ----------------
// p0=ln_w p1=ln_b p2=q_w p3=q_b p4=k_w p5=k_b p6=v_w p7=v_b
// p8=qf_w p9=qf_b p10=kf_w p11=kf_b p12=g_w p13=g_b p14=o_w p15=o_b
__global__ void prep_params(
    const void* p0, const void* p1, const void* p2, const void* p3,
    const void* p4, const void* p5, const void* p6, const void* p7,
    const void* p8, const void* p9, const void* p10, const void* p11,
    const void* p12, const void* p13, const void* p14, const void* p15,
    const u32* __restrict__ flag, u16* __restrict__ dst){
    bool bf = (*flag != 0u);
    int b = blockIdx.x, tid = threadIdx.x;
    if(b < NCONV){
        int idx = b*256 + tid;
        if(idx >= P_TOT) return;
        const int offs[17] = {P_LNW,P_LNB,P_QW,P_QB,P_KW,P_KB,P_VW,P_VB,
                              P_QFW,P_QFB,P_KFW,P_KFB,P_GW,P_GB,P_OW,P_OB,P_TOT};
        const void* ptrs[16] = {p0,p1,p2,p3,p4,p5,p6,p7,p8,p9,p10,p11,p12,p13,p14,p15};
        int tsel = 0;
        #pragma unroll
        for(int i=1;i<16;++i) if(idx >= offs[i]) tsel = i;
        dst[idx] = bf ? ((const u16*)ptrs[tsel])[idx - offs[tsel]]
                      : f2bf(((const float*)ptrs[tsel])[idx - offs[tsel]]);
    } else if(b < NCONV + 128){
        // combined weights: Wc[h][j][c] = sum_d F[j][d] * W[h*32+d][c]
        int idx = (b - NCONV)*256 + tid;            // [0, 32768)
        int sel = idx >> 14;                        // 0=q, 1=k
        int rem = idx & 16383;
        int h = rem >> 12, j = (rem >> 7) & 31, c = rem & 127;
        const void* FWp = sel ? p10 : p8;
        const void* Wp  = sel ? p4  : p2;
        float s = 0.f;
        #pragma unroll
        for(int d=0; d<32; ++d)
            s += ldp(FWp, j*32+d, bf) * ldp(Wp, (h*32+d)*128 + c, bf);
        dst[(sel ? P_CKW : P_CQW) + h*4096 + j*128 + c] = f2bf(s);
    } else {
        // combined biases: bc[h][j] = sum_d F[j][d]*b[h*32+d] + fb[j]
        int t = tid;
        int sel = t >> 7, h = (t >> 5) & 3, j = t & 31;
        const void* FWp = sel ? p10 : p8;
        const void* FBp = sel ? p11 : p9;
        const void* Bp  = sel ? p5  : p3;
        float s = ldp(FBp, j, bf);
        #pragma unroll
        for(int d=0; d<32; ++d)
            s += ldp(FWp, j*32+d, bf) * ldp(Bp, h*32+d, bf);
        dst[(sel ? P_CKB : P_CQB) + h*32 + j] = f2bf(s);
    }
}

// ---------------- LayerNorm: one wave per token ----------------
__global__ void ln_kernel(const void* __restrict__ zv, const u16* __restrict__ pb,
                          const u32* __restrict__ flag, u16* __restrict__ zn){
    int t = blockIdx.x*4 + (threadIdx.x>>6);
    int lane = threadIdx.x & 63;
    float x0, x1;
    if(*flag){
        u32 pr = ((const u32*)zv)[(size_t)t*64 + lane];
        x0 = __uint_as_float(pr<<16); x1 = __uint_as_float(pr & 0xffff0000u);
    } else {
        float2 v = ((const float2*)zv)[(size_t)t*64 + lane];
        x0 = v.x; x1 = v.y;
    }
    float s = x0 + x1, s2 = x0*x0 + x1*x1;
    #pragma unroll
    for(int o=1;o<64;o<<=1){ s += __shfl_xor(s,o,64); s2 += __shfl_xor(s2,o,64); }
    float mean = s*(1.f/128.f);
    float var  = s2*(1.f/128.f) - mean*mean;
    float rs = rsqrtf(var + 1e-5f);
    int c0 = 2*lane;
    float w0 = bf2f(pb[P_LNW+c0]), w1 = bf2f(pb[P_LNW+c0+1]);
    float b0 = bf2f(pb[P_LNB+c0]), b1 = bf2f(pb[P_LNB+c0+1]);
    float o0 = (x0-mean)*rs*w0 + b0;
    float o1 = (x1-mean)*rs*w1 + b1;
    u32 po = (u32)f2bf(o0) | ((u32)f2bf(o1)<<16);
    *(u32*)(zn + (size_t)t*128 + c0) = po;
}

// ---------------- mega kernel: ONE BLOCK PER (row, head) ----------------
// LDS (bytes):
//   mask_f [256 f32]      @ 0       (1024)
//   kfT    [64][264] u16  @ 1024    (33792)  kf^T [feature][n], masked
//   vT     [32][264] u16  @ 34816   (16896)  v^T [d][n] masked
//   qf     [256][68] u16  @ 1024    (34816)  aliases kfT+vT; [n][feature]
//   kvT    [33][68]  u16  @ 51712   (4488)   kv^T [d][f]; row 32 = ksum
#define ST_N 264
#define ST_F 68
#define SM_KF   1024
#define SM_VT   34816
#define SM_QF   1024
#define SM_KVT  51712
#define SM_TOT  56200

__global__ __launch_bounds__(256,2)
void mega_kernel(const u16* __restrict__ zn, const int* __restrict__ mask,
                 const u16* __restrict__ pb, u16* __restrict__ attn){
    __shared__ __align__(16) char smem[SM_TOT];
    float* mask_f = (float*)smem;
    u16* kfT = (u16*)(smem + SM_KF);
    u16* vT  = (u16*)(smem + SM_VT);
    u16* qf  = (u16*)(smem + SM_QF);
    u16* kvT = (u16*)(smem + SM_KVT);

    int g = blockIdx.x, row = g>>2, h = g&3;
    int tid = threadIdx.x, lane = tid & 63, wv = tid >> 6;
    int lm = lane & 15, quad = lane >> 4;

    mask_f[tid] = (float)mask[row*256 + tid];

    // zn A-frags: loaded once, reused by all 5 GEMM phases
    bh8 a[4][4];
    {
        const u16* Ab = zn + ((size_t)row*256 + wv*64 + lm)*128 + quad*8;
        #pragma unroll
        for(int mt=0; mt<4; ++mt)
            #pragma unroll
            for(int ks=0; ks<4; ++ks)
                a[mt][ks] = ld_frag(Ab + (size_t)mt*16*128 + ks*32);
    }
    bh8 onesf;
    { union{int4 i; bh8 h;} u; u.i.x=u.i.y=u.i.z=u.i.w=0x3F803F80; onesf = u.h; }

    __syncthreads();

    f32x4 gacc[4][2];
    // ---- phase 1a: m_k = zn·Wc_k^T + bc_k -> clip/exp -> kfT (masked) ----
    {
        f32x4 acc[4][2];
        #pragma unroll
        for(int mt=0;mt<4;++mt){ acc[mt][0]=(f32x4){0,0,0,0}; acc[mt][1]=(f32x4){0,0,0,0}; }
        #pragma unroll
        for(int ks=0; ks<4; ++ks){
            bh8 b0 = ld_frag(pb + P_CKW + h*4096 + lm*128      + ks*32 + quad*8);
            bh8 b1 = ld_frag(pb + P_CKW + h*4096 + (16+lm)*128 + ks*32 + quad*8);
            #pragma unroll
            for(int mt=0; mt<4; ++mt){
                acc[mt][0] = MFMA(a[mt][ks], b0, acc[mt][0], 0,0,0);
                acc[mt][1] = MFMA(a[mt][ks], b1, acc[mt][1], 0,0,0);
            }
        }
        float bb0 = bf2f(pb[P_CKB + h*32 + lm]);
        float bb1 = bf2f(pb[P_CKB + h*32 + 16 + lm]);
        #pragma unroll
        for(int mt=0; mt<4; ++mt){
            int n0 = wv*64 + mt*16 + quad*4;
            float e0p[4], e0m[4], e1p[4], e1m[4];
            #pragma unroll
            for(int r=0; r<4; ++r){
                float mk = mask_f[n0+r];
                float m0 = fminf(8.f, fmaxf(-8.f, acc[mt][0][r] + bb0));
                float m1 = fminf(8.f, fmaxf(-8.f, acc[mt][1][r] + bb1));
                e0p[r] = __expf( m0)*mk;  e0m[r] = __expf(-m0)*mk;
                e1p[r] = __expf( m1)*mk;  e1m[r] = __expf(-m1)*mk;
            }
            *(int2*)(kfT + (size_t)(lm   )*ST_N + n0) = pk4(e0p[0],e0p[1],e0p[2],e0p[3]);
            *(int2*)(kfT + (size_t)(lm+32)*ST_N + n0) = pk4(e0m[0],e0m[1],e0m[2],e0m[3]);
            *(int2*)(kfT + (size_t)(lm+16)*ST_N + n0) = pk4(e1p[0],e1p[1],e1p[2],e1p[3]);
            *(int2*)(kfT + (size_t)(lm+48)*ST_N + n0) = pk4(e1m[0],e1m[1],e1m[2],e1m[3]);
        }
    }
    // ---- phase 1b: v = (zn·Wv_h^T + vb)*mask -> vT ----
    {
        f32x4 acc[4][2];
        #pragma unroll
        for(int mt=0;mt<4;++mt){ acc[mt][0]=(f32x4){0,0,0,0}; acc[mt][1]=(f32x4){0,0,0,0}; }
        #pragma unroll
        for(int ks=0; ks<4; ++ks){
            bh8 b0 = ld_frag(pb + P_VW + (size_t)(h*32 + lm)*128      + ks*32 + quad*8);
            bh8 b1 = ld_frag(pb + P_VW + (size_t)(h*32 + 16 + lm)*128 + ks*32 + quad*8);
            #pragma unroll
            for(int mt=0; mt<4; ++mt){
                acc[mt][0] = MFMA(a[mt][ks], b0, acc[mt][0], 0,0,0);
                acc[mt][1] = MFMA(a[mt][ks], b1, acc[mt][1], 0,0,0);
            }
        }
        float bb0 = bf2f(pb[P_VB + h*32 + lm]);
        float bb1 = bf2f(pb[P_VB + h*32 + 16 + lm]);
        #pragma unroll
        for(int mt=0; mt<4; ++mt){
            int n0 = wv*64 + mt*16 + quad*4;
            float v0[4], v1[4];
            #pragma unroll
            for(int r=0; r<4; ++r){
                float mk = mask_f[n0+r];
                v0[r] = (acc[mt][0][r] + bb0)*mk;
                v1[r] = (acc[mt][1][r] + bb1)*mk;
            }
            *(int2*)(vT + (size_t)(lm   )*ST_N + n0) = pk4(v0[0],v0[1],v0[2],v0[3]);
            *(int2*)(vT + (size_t)(16+lm)*ST_N + n0) = pk4(v1[0],v1[1],v1[2],v1[3]);
        }
    }
    // ---- phase 1c: gate = sigmoid(zn·Wg_h^T + gb) -> registers ----
    {
        f32x4 acc[4][2];
        #pragma unroll
        for(int mt=0;mt<4;++mt){ acc[mt][0]=(f32x4){0,0,0,0}; acc[mt][1]=(f32x4){0,0,0,0}; }
        #pragma unroll
        for(int ks=0; ks<4; ++ks){
            bh8 b0 = ld_frag(pb + P_GW + (size_t)(h*32 + lm)*128      + ks*32 + quad*8);
            bh8 b1 = ld_frag(pb + P_GW + (size_t)(h*32 + 16 + lm)*128 + ks*32 + quad*8);
            #pragma unroll
            for(int mt=0; mt<4; ++mt){
                acc[mt][0] = MFMA(a[mt][ks], b0, acc[mt][0], 0,0,0);
                acc[mt][1] = MFMA(a[mt][ks], b1, acc[mt][1], 0,0,0);
            }
        }
        float bb0 = bf2f(pb[P_GB + h*32 + lm]);
        float bb1 = bf2f(pb[P_GB + h*32 + 16 + lm]);
        #pragma unroll
        for(int mt=0; mt<4; ++mt)
            #pragma unroll
            for(int r=0; r<4; ++r){
                gacc[mt][0][r] = 1.f/(1.f + __expf(-(acc[mt][0][r] + bb0)));
                gacc[mt][1][r] = 1.f/(1.f + __expf(-(acc[mt][1][r] + bb1)));
            }
    }
    __syncthreads();
    // ---- phase 2: kvT[d][f] = sum_n kfT[f][n]*vT[d][n]; ksum via ones-frag ----
    {
        f32x4 acc0=(f32x4){0,0,0,0}, acc1=(f32x4){0,0,0,0}, acc2=(f32x4){0,0,0,0};
        #pragma unroll
        for(int ks=0; ks<8; ++ks){
            bh8 aa = ld_frag(kfT + (size_t)(wv*16+lm)*ST_N + ks*32 + quad*8);
            bh8 b0 = ld_frag(vT + (size_t)lm*ST_N      + ks*32 + quad*8);
            bh8 b1 = ld_frag(vT + (size_t)(16+lm)*ST_N + ks*32 + quad*8);
            acc0 = MFMA(aa, b0, acc0, 0,0,0);
            acc1 = MFMA(aa, b1, acc1, 0,0,0);
            acc2 = MFMA(aa, onesf, acc2, 0,0,0);
        }
        int f0 = wv*16 + quad*4;
        *(int2*)(kvT + (size_t)(lm   )*ST_F + f0) = pk4(acc0[0],acc0[1],acc0[2],acc0[3]);
        *(int2*)(kvT + (size_t)(16+lm)*ST_F + f0) = pk4(acc1[0],acc1[1],acc1[2],acc1[3]);
        if(lm==0)
            *(int2*)(kvT + (size_t)32*ST_F + f0) = pk4(acc2[0],acc2[1],acc2[2],acc2[3]);
    }
    __syncthreads();
    // ---- phase 3: m_q = zn·Wc_q^T + bc_q -> clip/exp -> qf [n][f] (aliases kfT/vT) ----
    {
        f32x4 acc[4][2];
        #pragma unroll
        for(int mt=0;mt<4;++mt){ acc[mt][0]=(f32x4){0,0,0,0}; acc[mt][1]=(f32x4){0,0,0,0}; }
        #pragma unroll
        for(int ks=0; ks<4; ++ks){
            bh8 b0 = ld_frag(pb + P_CQW + h*4096 + lm*128      + ks*32 + quad*8);
            bh8 b1 = ld_frag(pb + P_CQW + h*4096 + (16+lm)*128 + ks*32 + quad*8);
            #pragma unroll
            for(int mt=0; mt<4; ++mt){
                acc[mt][0] = MFMA(a[mt][ks], b0, acc[mt][0], 0,0,0);
                acc[mt][1] = MFMA(a[mt][ks], b1, acc[mt][1], 0,0,0);
            }
        }
        float bb0 = bf2f(pb[P_CQB + h*32 + lm]);
        float bb1 = bf2f(pb[P_CQB + h*32 + 16 + lm]);
        #pragma unroll
        for(int mt=0; mt<4; ++mt)
            #pragma unroll
            for(int r=0; r<4; ++r){
                int n = wv*64 + mt*16 + quad*4 + r;
                float m0 = fminf(8.f, fmaxf(-8.f, acc[mt][0][r] + bb0));
                float m1 = fminf(8.f, fmaxf(-8.f, acc[mt][1][r] + bb1));
                qf[n*ST_F + lm     ] = f2bf(__expf( m0));
                qf[n*ST_F + lm + 32] = f2bf(__expf(-m0));
                qf[n*ST_F + lm + 16] = f2bf(__expf( m1));
                qf[n*ST_F + lm + 48] = f2bf(__expf(-m1));
            }
    }
    __syncthreads();
    // ---- phase 4: out = (qf·kvT^T)/den * gate ----
    {
        f32x4 acc[4][3];
        #pragma unroll
        for(int mt=0;mt<4;++mt)
            #pragma unroll
            for(int nt=0;nt<3;++nt) acc[mt][nt]=(f32x4){0,0,0,0};
        #pragma unroll
        for(int ks=0; ks<2; ++ks){
            bh8 b0 = ld_frag(kvT + (size_t)lm*ST_F      + ks*32 + quad*8);
            bh8 b1 = ld_frag(kvT + (size_t)(16+lm)*ST_F + ks*32 + quad*8);
            bh8 b2 = ld_frag(kvT + (size_t)32*ST_F      + ks*32 + quad*8); // ksum, broadcast
            #pragma unroll
            for(int mt=0; mt<4; ++mt){
                bh8 aa = ld_frag(qf + (size_t)(wv*64+mt*16+lm)*ST_F + ks*32 + quad*8);
                acc[mt][0] = MFMA(aa, b0, acc[mt][0], 0,0,0);
                acc[mt][1] = MFMA(aa, b1, acc[mt][1], 0,0,0);
                acc[mt][2] = MFMA(aa, b2, acc[mt][2], 0,0,0);
            }
        }
        #pragma unroll
        for(int mt=0; mt<4; ++mt)
            #pragma unroll
            for(int r=0; r<4; ++r){
                int n = wv*64 + mt*16 + quad*4 + r;
                float rcp = 1.f / fmaxf(acc[mt][2][r], 1e-6f);
                u16* op = attn + ((size_t)row*256 + n)*128 + h*32;
                op[lm]    = f2bf(acc[mt][0][r]*rcp*gacc[mt][0][r]);
                op[16+lm] = f2bf(acc[mt][1][r]*rcp*gacc[mt][1][r]);
            }
    }
}

// ---------------- MFMA o-proj: attn -> out (x mask, dual dtype store) ----------------
#define LDS_P 136
__global__ __launch_bounds__(256,2)
void oproj_kernel(const u16* __restrict__ attn, const u16* __restrict__ pb,
                  const int* __restrict__ mask, const u32* __restrict__ flagp,
                  void* __restrict__ out){
    __shared__ u16 st[128*LDS_P];
    int tid = threadIdx.x;
    int lane = tid&63, wv = tid>>6;
    int mhalf = (wv>>1)*64, nhalf = (wv&1)*64;
    int lm = lane&15, quad = lane>>4;
    int m0 = blockIdx.x*128;

    f32x4 acc[4][4];
    #pragma unroll
    for(int mt=0;mt<4;++mt)
        #pragma unroll
        for(int nt=0;nt<4;++nt)
            acc[mt][nt] = (f32x4){0.f,0.f,0.f,0.f};

    const u16* Abase = attn + (size_t)(m0 + mhalf + lm)*128 + quad*8;
    const u16* W = pb + P_OW;
    #pragma unroll
    for(int ks=0; ks<4; ++ks){
        bh8 a[4], b[4];
        #pragma unroll
        for(int mt=0; mt<4; ++mt)
            a[mt] = ld_frag(Abase + (size_t)mt*16*128 + ks*32);
        #pragma unroll
        for(int nt=0; nt<4; ++nt)
            b[nt] = ld_frag(W + (size_t)(nhalf + nt*16 + lm)*128 + ks*32 + quad*8);
        #pragma unroll
        for(int mt=0; mt<4; ++mt)
            #pragma unroll
            for(int nt=0; nt<4; ++nt)
                acc[mt][nt] = MFMA(a[mt], b[nt], acc[mt][nt], 0, 0, 0);
    }
    float bv[4];
    #pragma unroll
    for(int nt=0; nt<4; ++nt) bv[nt] = bf2f(pb[P_OB + nhalf + nt*16 + lm]);
    #pragma unroll
    for(int mt=0; mt<4; ++mt){
        int mrow = m0 + mhalf + mt*16 + quad*4;
        float mk[4];
        #pragma unroll
        for(int r=0;r<4;++r) mk[r] = (float)mask[mrow+r];
        #pragma unroll
        for(int nt=0; nt<4; ++nt)
            #pragma unroll
            for(int r=0; r<4; ++r){
                float x = (acc[mt][nt][r] + bv[nt]) * mk[r];
                st[(mhalf + mt*16 + quad*4 + r)*LDS_P + nhalf + nt*16 + lm] = f2bf(x);
            }
    }
    __syncthreads();
    {
        int row = tid>>1, half = tid&1;
        const u16* src = st + row*LDS_P + half*64;
        bool isbf = (*flagp != 0u);
        if(isbf){
            u16* dst = (u16*)out + (size_t)(m0 + row)*128 + half*64;
            #pragma unroll
            for(int it=0; it<8; ++it)
                ((int4*)dst)[it] = ((const int4*)src)[it];
        } else {
            float* dst = (float*)out + (size_t)(m0 + row)*128 + half*64;
            #pragma unroll
            for(int it=0; it<8; ++it){
                float f[8]; cvt8(((const int4*)src)[it], f);
                float4 lo; lo.x=f[0]; lo.y=f[1]; lo.z=f[2]; lo.w=f[3];
                float4 hi; hi.x=f[4]; hi.y=f[5]; hi.z=f[6]; hi.w=f[7];
                ((float4*)dst)[it*2  ] = lo;
                ((float4*)dst)[it*2+1] = hi;
            }
        }
    }
}

// ---------------- launch ----------------
extern "C" void kernel_launch(void* const* d_in, const int* in_sizes, int n_in,
                              void* d_out, int out_size, void* d_ws, size_t ws_size,
                              hipStream_t stream){
    const void* z    = d_in[0];
    const int*  mask = (const int*)d_in[1];

    char* ws = (char*)d_ws;
    const size_t MB = (size_t)1<<20;
    u16*   zn   = (u16*)(ws + 0*MB);      // 16 MB  [t][128] bf16
    u16*   attn = (u16*)(ws + 16*MB);     // 16 MB  [t][128] bf16
    u16*   pb   = (u16*)(ws + 32*MB);     // ~231 KB bf16 param block (incl. combined weights)
    u32*   flag = (u32*)(ws + 33*MB);     // 4 B dtype flag

    detect_kernel<<<1,256,0,stream>>>((const u32*)z, flag);
    prep_params<<<NCONV+129,256,0,stream>>>(
        d_in[2], d_in[3], d_in[4], d_in[5], d_in[6], d_in[7], d_in[8], d_in[9],
        d_in[10], d_in[11], d_in[12], d_in[13], d_in[14], d_in[15], d_in[16], d_in[17],
        flag, pb);
    ln_kernel<<<16384,256,0,stream>>>(z, pb, flag, zn);
    mega_kernel<<<1024,256,0,stream>>>(zn, mask, pb, attn);
    oproj_kernel<<<512,256,0,stream>>>(attn, pb, mask, flag, d_out);
}

// Round 9
// 183.041 us; speedup vs baseline: 1.0360x; 1.0360x over previous
//
#include <hip/hip_runtime.h>
#include <stdint.h>

#define DEV __device__ __forceinline__

typedef unsigned short u16;
typedef unsigned int u32;
typedef short bh8 __attribute__((ext_vector_type(8)));
typedef float f32x4 __attribute__((ext_vector_type(4)));

// ---------- bf16 helpers ----------
DEV float bf2f(u16 v){ return __uint_as_float(((u32)v)<<16); }
DEV u16 f2bf(float f){
    u32 x = __float_as_uint(f);
    x += 0x7fffu + ((x>>16)&1u);
    return (u16)(x>>16);
}
DEV void cvt8(int4 r, float* f){
    u32 a=(u32)r.x, b=(u32)r.y, c=(u32)r.z, d=(u32)r.w;
    f[0]=__uint_as_float(a<<16); f[1]=__uint_as_float(a&0xffff0000u);
    f[2]=__uint_as_float(b<<16); f[3]=__uint_as_float(b&0xffff0000u);
    f[4]=__uint_as_float(c<<16); f[5]=__uint_as_float(c&0xffff0000u);
    f[6]=__uint_as_float(d<<16); f[7]=__uint_as_float(d&0xffff0000u);
}
DEV int2 pk4(float a, float b, float c, float d){
    int2 r;
    r.x = (int)((u32)f2bf(a) | ((u32)f2bf(b)<<16));
    r.y = (int)((u32)f2bf(c) | ((u32)f2bf(d)<<16));
    return r;
}
DEV bh8 ld_frag(const u16* p){
    int4 v = *(const int4*)p;
    union{ int4 i; bh8 h; } u; u.i = v; return u.h;
}
#define MFMA __builtin_amdgcn_mfma_f32_16x16x32_bf16

// Problem constants: BSZ=1, S=256, C=128, H=4, D=32, F=64.
// I/O dtype: f32 (R7: bf16-read -> NaN; R8 first launch: f32 in/out passed). bf16 internal.

// Param block layout (elements, bf16) inside workspace (R6-verified):
#define P_LNW 0
#define P_LNB 128
#define P_QW  256
#define P_QB  16640
#define P_KW  16768
#define P_KB  33152
#define P_VW  33280
#define P_VB  49664
#define P_QFW 49792
#define P_QFB 50816
#define P_KFW 50848
#define P_KFB 51872
#define P_GW  51904
#define P_GB  68288
#define P_OW  68416
#define P_OB  84800
#define P_TOT 84928
// combined feature-map weights (appended):
#define P_CQW 84928    // [h][j][c] 4*32*128
#define P_CQB 101312   // [h][j]    4*32
#define P_CKW 101440
#define P_CKB 117824

#define NCONV 332      // blocks for the convert part (332*256 >= P_TOT)

// ---------------- params: f32 -> bf16 block + combined q/k feature weights ----------------
// p0=ln_w p1=ln_b p2=q_w p3=q_b p4=k_w p5=k_b p6=v_w p7=v_b
// p8=qf_w p9=qf_b p10=kf_w p11=kf_b p12=g_w p13=g_b p14=o_w p15=o_b
__global__ void prep_params(
    const float* p0, const float* p1, const float* p2, const float* p3,
    const float* p4, const float* p5, const float* p6, const float* p7,
    const float* p8, const float* p9, const float* p10, const float* p11,
    const float* p12, const float* p13, const float* p14, const float* p15,
    u16* __restrict__ dst){
    int b = blockIdx.x, tid = threadIdx.x;
    if(b < NCONV){
        int idx = b*256 + tid;
        if(idx >= P_TOT) return;
        const int offs[17] = {P_LNW,P_LNB,P_QW,P_QB,P_KW,P_KB,P_VW,P_VB,
                              P_QFW,P_QFB,P_KFW,P_KFB,P_GW,P_GB,P_OW,P_OB,P_TOT};
        const float* ptrs[16] = {p0,p1,p2,p3,p4,p5,p6,p7,p8,p9,p10,p11,p12,p13,p14,p15};
        int tsel = 0;
        #pragma unroll
        for(int i=1;i<16;++i) if(idx >= offs[i]) tsel = i;
        dst[idx] = f2bf(ptrs[tsel][idx - offs[tsel]]);
    } else if(b < NCONV + 128){
        // combined weights: Wc[h][j][c] = sum_d F[j][d] * W[h*32+d][c]
        int idx = (b - NCONV)*256 + tid;            // [0, 32768)
        int sel = idx >> 14;                        // 0=q, 1=k
        int rem = idx & 16383;
        int h = rem >> 12, j = (rem >> 7) & 31, c = rem & 127;
        const float* FWp = sel ? p10 : p8;
        const float* Wp  = sel ? p4  : p2;
        float s = 0.f;
        #pragma unroll
        for(int d=0; d<32; ++d)
            s += FWp[j*32+d] * Wp[(h*32+d)*128 + c];
        dst[(sel ? P_CKW : P_CQW) + h*4096 + j*128 + c] = f2bf(s);
    } else {
        // combined biases: bc[h][j] = sum_d F[j][d]*b[h*32+d] + fb[j]
        int t = tid;
        int sel = t >> 7, h = (t >> 5) & 3, j = t & 31;
        const float* FWp = sel ? p10 : p8;
        const float* FBp = sel ? p11 : p9;
        const float* Bp  = sel ? p5  : p3;
        float s = FBp[j];
        #pragma unroll
        for(int d=0; d<32; ++d)
            s += FWp[j*32+d] * Bp[h*32+d];
        dst[(sel ? P_CKB : P_CQB) + h*32 + j] = f2bf(s);
    }
}

// ---------------- LayerNorm: one wave per token (f32 in, bf16 out) ----------------
__global__ void ln_kernel(const float* __restrict__ zv, const u16* __restrict__ pb,
                          u16* __restrict__ zn){
    int t = blockIdx.x*4 + (threadIdx.x>>6);
    int lane = threadIdx.x & 63;
    float2 v = ((const float2*)zv)[(size_t)t*64 + lane];
    float x0 = v.x, x1 = v.y;
    float s = x0 + x1, s2 = x0*x0 + x1*x1;
    #pragma unroll
    for(int o=1;o<64;o<<=1){ s += __shfl_xor(s,o,64); s2 += __shfl_xor(s2,o,64); }
    float mean = s*(1.f/128.f);
    float var  = s2*(1.f/128.f) - mean*mean;
    float rs = rsqrtf(var + 1e-5f);
    int c0 = 2*lane;
    float w0 = bf2f(pb[P_LNW+c0]), w1 = bf2f(pb[P_LNW+c0+1]);
    float b0 = bf2f(pb[P_LNB+c0]), b1 = bf2f(pb[P_LNB+c0+1]);
    float o0 = (x0-mean)*rs*w0 + b0;
    float o1 = (x1-mean)*rs*w1 + b1;
    u32 po = (u32)f2bf(o0) | ((u32)f2bf(o1)<<16);
    *(u32*)(zn + (size_t)t*128 + c0) = po;
}

// ---------------- mega kernel: one block per (row, head) [R6-verified body] ----------------
// LDS (bytes):
//   mask_f [256 f32]      @ 0       (1024)
//   kfT    [64][264] u16  @ 1024    (33792)  kf^T [f][n], masked
//   vT     [32][264] u16  @ 34816   (16896)  v^T [d][n] masked
//   qf     [256][68] u16  @ 1024    (34816)  aliases kfT(+vT head); [n][f]
//   kvT    [33][68]  u16  @ 51712   (4488)   kv^T [d][f]; row 32 = ksum
#define ST_N 264
#define ST_F 68
#define SM_KF   1024
#define SM_VT   34816
#define SM_QF   1024
#define SM_KVT  51712
#define SM_TOT  56200

__global__ __launch_bounds__(256,2)
void mega_kernel(const u16* __restrict__ zn, const int* __restrict__ mask,
                 const u16* __restrict__ pb, u16* __restrict__ attn){
    __shared__ __align__(16) char smem[SM_TOT];
    float* mask_f = (float*)smem;
    u16* kfT = (u16*)(smem + SM_KF);
    u16* vT  = (u16*)(smem + SM_VT);
    u16* qf  = (u16*)(smem + SM_QF);
    u16* kvT = (u16*)(smem + SM_KVT);

    int g = blockIdx.x, row = g>>2, h = g&3;
    int tid = threadIdx.x, lane = tid & 63, wv = tid >> 6;
    int lm = lane & 15, quad = lane >> 4;

    mask_f[tid] = (float)mask[row*256 + tid];

    // zn A-frags: loaded once, reused by all GEMM phases
    bh8 a[4][4];
    {
        const u16* Ab = zn + ((size_t)row*256 + wv*64 + lm)*128 + quad*8;
        #pragma unroll
        for(int mt=0; mt<4; ++mt)
            #pragma unroll
            for(int ks=0; ks<4; ++ks)
                a[mt][ks] = ld_frag(Ab + (size_t)mt*16*128 + ks*32);
    }
    bh8 onesf;
    { union{int4 i; bh8 h;} u; u.i.x=u.i.y=u.i.z=u.i.w=0x3F803F80; onesf = u.h; }

    __syncthreads();

    f32x4 gacc[4][2];
    // ---- phase 1 (merged): B = [ck0 ck1 | v0 v1 | g0 g1], shared A ----
    {
        f32x4 acc[4][6];
        #pragma unroll
        for(int mt=0;mt<4;++mt)
            #pragma unroll
            for(int j=0;j<6;++j) acc[mt][j] = (f32x4){0,0,0,0};
        #pragma unroll
        for(int ks=0; ks<4; ++ks){
            bh8 b[6];
            b[0] = ld_frag(pb + P_CKW + h*4096 + lm*128            + ks*32 + quad*8);
            b[1] = ld_frag(pb + P_CKW + h*4096 + (16+lm)*128       + ks*32 + quad*8);
            b[2] = ld_frag(pb + P_VW + (size_t)(h*32 + lm)*128     + ks*32 + quad*8);
            b[3] = ld_frag(pb + P_VW + (size_t)(h*32 + 16+lm)*128  + ks*32 + quad*8);
            b[4] = ld_frag(pb + P_GW + (size_t)(h*32 + lm)*128     + ks*32 + quad*8);
            b[5] = ld_frag(pb + P_GW + (size_t)(h*32 + 16+lm)*128  + ks*32 + quad*8);
            #pragma unroll
            for(int mt=0; mt<4; ++mt)
                #pragma unroll
                for(int j=0;j<6;++j)
                    acc[mt][j] = MFMA(a[mt][ks], b[j], acc[mt][j], 0,0,0);
        }
        float bk0 = bf2f(pb[P_CKB + h*32 + lm]);
        float bk1 = bf2f(pb[P_CKB + h*32 + 16 + lm]);
        float bv0 = bf2f(pb[P_VB + h*32 + lm]);
        float bv1 = bf2f(pb[P_VB + h*32 + 16 + lm]);
        float bg0 = bf2f(pb[P_GB + h*32 + lm]);
        float bg1 = bf2f(pb[P_GB + h*32 + 16 + lm]);
        #pragma unroll
        for(int mt=0; mt<4; ++mt){
            int n0 = wv*64 + mt*16 + quad*4;
            float ep0[4], em0[4], ep1[4], em1[4], v0[4], v1[4];
            #pragma unroll
            for(int r=0; r<4; ++r){
                float mk = mask_f[n0+r];
                float m0 = fminf(8.f, fmaxf(-8.f, acc[mt][0][r] + bk0));
                float m1 = fminf(8.f, fmaxf(-8.f, acc[mt][1][r] + bk1));
                ep0[r] = __expf( m0)*mk;  em0[r] = __expf(-m0)*mk;
                ep1[r] = __expf( m1)*mk;  em1[r] = __expf(-m1)*mk;
                v0[r] = (acc[mt][2][r] + bv0)*mk;
                v1[r] = (acc[mt][3][r] + bv1)*mk;
                gacc[mt][0][r] = 1.f/(1.f + __expf(-(acc[mt][4][r] + bg0)));
                gacc[mt][1][r] = 1.f/(1.f + __expf(-(acc[mt][5][r] + bg1)));
            }
            *(int2*)(kfT + (size_t)(lm   )*ST_N + n0) = pk4(ep0[0],ep0[1],ep0[2],ep0[3]);
            *(int2*)(kfT + (size_t)(lm+32)*ST_N + n0) = pk4(em0[0],em0[1],em0[2],em0[3]);
            *(int2*)(kfT + (size_t)(lm+16)*ST_N + n0) = pk4(ep1[0],ep1[1],ep1[2],ep1[3]);
            *(int2*)(kfT + (size_t)(lm+48)*ST_N + n0) = pk4(em1[0],em1[1],em1[2],em1[3]);
            *(int2*)(vT  + (size_t)(lm   )*ST_N + n0) = pk4(v0[0],v0[1],v0[2],v0[3]);
            *(int2*)(vT  + (size_t)(16+lm)*ST_N + n0) = pk4(v1[0],v1[1],v1[2],v1[3]);
        }
    }
    __syncthreads();
    // ---- phase 2: kvT[d][f] = sum_n kfT[f][n]*vT[d][n]; ksum via ones-frag ----
    {
        f32x4 acc0=(f32x4){0,0,0,0}, acc1=(f32x4){0,0,0,0}, acc2=(f32x4){0,0,0,0};
        #pragma unroll
        for(int ks=0; ks<8; ++ks){
            bh8 aa = ld_frag(kfT + (size_t)(wv*16+lm)*ST_N + ks*32 + quad*8);
            bh8 b0 = ld_frag(vT + (size_t)lm*ST_N      + ks*32 + quad*8);
            bh8 b1 = ld_frag(vT + (size_t)(16+lm)*ST_N + ks*32 + quad*8);
            acc0 = MFMA(aa, b0, acc0, 0,0,0);
            acc1 = MFMA(aa, b1, acc1, 0,0,0);
            acc2 = MFMA(aa, onesf, acc2, 0,0,0);
        }
        int f0 = wv*16 + quad*4;
        *(int2*)(kvT + (size_t)(lm   )*ST_F + f0) = pk4(acc0[0],acc0[1],acc0[2],acc0[3]);
        *(int2*)(kvT + (size_t)(16+lm)*ST_F + f0) = pk4(acc1[0],acc1[1],acc1[2],acc1[3]);
        if(lm==0)
            *(int2*)(kvT + (size_t)32*ST_F + f0) = pk4(acc2[0],acc2[1],acc2[2],acc2[3]);
    }
    __syncthreads();
    // ---- phase 3: qf[n][f] = featmap(zn·Wc_q^T + bc_q)  (aliases kfT/vT) ----
    {
        f32x4 acc[4][2];
        #pragma unroll
        for(int mt=0;mt<4;++mt){ acc[mt][0]=(f32x4){0,0,0,0}; acc[mt][1]=(f32x4){0,0,0,0}; }
        #pragma unroll
        for(int ks=0; ks<4; ++ks){
            bh8 b0 = ld_frag(pb + P_CQW + h*4096 + lm*128      + ks*32 + quad*8);
            bh8 b1 = ld_frag(pb + P_CQW + h*4096 + (16+lm)*128 + ks*32 + quad*8);
            #pragma unroll
            for(int mt=0; mt<4; ++mt){
                acc[mt][0] = MFMA(a[mt][ks], b0, acc[mt][0], 0,0,0);
                acc[mt][1] = MFMA(a[mt][ks], b1, acc[mt][1], 0,0,0);
            }
        }
        float bb0 = bf2f(pb[P_CQB + h*32 + lm]);
        float bb1 = bf2f(pb[P_CQB + h*32 + 16 + lm]);
        #pragma unroll
        for(int mt=0; mt<4; ++mt)
            #pragma unroll
            for(int r=0; r<4; ++r){
                int n = wv*64 + mt*16 + quad*4 + r;
                float m0 = fminf(8.f, fmaxf(-8.f, acc[mt][0][r] + bb0));
                float m1 = fminf(8.f, fmaxf(-8.f, acc[mt][1][r] + bb1));
                qf[n*ST_F + lm     ] = f2bf(__expf( m0));
                qf[n*ST_F + lm + 32] = f2bf(__expf(-m0));
                qf[n*ST_F + lm + 16] = f2bf(__expf( m1));
                qf[n*ST_F + lm + 48] = f2bf(__expf(-m1));
            }
    }
    __syncthreads();
    // ---- phase 4: out = (qf·kvT^T)/den * gate ----
    {
        f32x4 acc[4][3];
        #pragma unroll
        for(int mt=0;mt<4;++mt)
            #pragma unroll
            for(int nt=0;nt<3;++nt) acc[mt][nt]=(f32x4){0,0,0,0};
        #pragma unroll
        for(int ks=0; ks<2; ++ks){
            bh8 b0 = ld_frag(kvT + (size_t)lm*ST_F      + ks*32 + quad*8);
            bh8 b1 = ld_frag(kvT + (size_t)(16+lm)*ST_F + ks*32 + quad*8);
            bh8 b2 = ld_frag(kvT + (size_t)32*ST_F      + ks*32 + quad*8); // ksum, broadcast
            #pragma unroll
            for(int mt=0; mt<4; ++mt){
                bh8 aa = ld_frag(qf + (size_t)(wv*64+mt*16+lm)*ST_F + ks*32 + quad*8);
                acc[mt][0] = MFMA(aa, b0, acc[mt][0], 0,0,0);
                acc[mt][1] = MFMA(aa, b1, acc[mt][1], 0,0,0);
                acc[mt][2] = MFMA(aa, b2, acc[mt][2], 0,0,0);
            }
        }
        #pragma unroll
        for(int mt=0; mt<4; ++mt)
            #pragma unroll
            for(int r=0; r<4; ++r){
                int n = wv*64 + mt*16 + quad*4 + r;
                float rcp = 1.f / fmaxf(acc[mt][2][r], 1e-6f);
                u16* op = attn + ((size_t)row*256 + n)*128 + h*32;
                op[lm]    = f2bf(acc[mt][0][r]*rcp*gacc[mt][0][r]);
                op[16+lm] = f2bf(acc[mt][1][r]*rcp*gacc[mt][1][r]);
            }
    }
}

// ---------------- MFMA o-proj: attn(bf16) -> out(f32), x mask ----------------
#define LDS_P 136
__global__ __launch_bounds__(256,2)
void oproj_kernel(const u16* __restrict__ attn, const u16* __restrict__ pb,
                  const int* __restrict__ mask, float* __restrict__ out){
    __shared__ u16 st[128*LDS_P];
    int tid = threadIdx.x;
    int lane = tid&63, wv = tid>>6;
    int mhalf = (wv>>1)*64, nhalf = (wv&1)*64;
    int lm = lane&15, quad = lane>>4;
    int m0 = blockIdx.x*128;

    f32x4 acc[4][4];
    #pragma unroll
    for(int mt=0;mt<4;++mt)
        #pragma unroll
        for(int nt=0;nt<4;++nt)
            acc[mt][nt] = (f32x4){0.f,0.f,0.f,0.f};

    const u16* Abase = attn + (size_t)(m0 + mhalf + lm)*128 + quad*8;
    const u16* W = pb + P_OW;
    #pragma unroll
    for(int ks=0; ks<4; ++ks){
        bh8 a[4], b[4];
        #pragma unroll
        for(int mt=0; mt<4; ++mt)
            a[mt] = ld_frag(Abase + (size_t)mt*16*128 + ks*32);
        #pragma unroll
        for(int nt=0; nt<4; ++nt)
            b[nt] = ld_frag(W + (size_t)(nhalf + nt*16 + lm)*128 + ks*32 + quad*8);
        #pragma unroll
        for(int mt=0; mt<4; ++mt)
            #pragma unroll
            for(int nt=0; nt<4; ++nt)
                acc[mt][nt] = MFMA(a[mt], b[nt], acc[mt][nt], 0, 0, 0);
    }
    float bv[4];
    #pragma unroll
    for(int nt=0; nt<4; ++nt) bv[nt] = bf2f(pb[P_OB + nhalf + nt*16 + lm]);
    #pragma unroll
    for(int mt=0; mt<4; ++mt){
        int mrow = m0 + mhalf + mt*16 + quad*4;
        float mk[4];
        #pragma unroll
        for(int r=0;r<4;++r) mk[r] = (float)mask[mrow+r];
        #pragma unroll
        for(int nt=0; nt<4; ++nt)
            #pragma unroll
            for(int r=0; r<4; ++r){
                float x = (acc[mt][nt][r] + bv[nt]) * mk[r];
                st[(mhalf + mt*16 + quad*4 + r)*LDS_P + nhalf + nt*16 + lm] = f2bf(x);
            }
    }
    __syncthreads();
    {
        int row = tid>>1, half = tid&1;
        const u16* src = st + row*LDS_P + half*64;
        float* dst = out + (size_t)(m0 + row)*128 + half*64;
        #pragma unroll
        for(int it=0; it<8; ++it){
            float f[8]; cvt8(((const int4*)src)[it], f);
            float4 lo; lo.x=f[0]; lo.y=f[1]; lo.z=f[2]; lo.w=f[3];
            float4 hi; hi.x=f[4]; hi.y=f[5]; hi.z=f[6]; hi.w=f[7];
            ((float4*)dst)[it*2  ] = lo;
            ((float4*)dst)[it*2+1] = hi;
        }
    }
}

// ---------------- launch ----------------
extern "C" void kernel_launch(void* const* d_in, const int* in_sizes, int n_in,
                              void* d_out, int out_size, void* d_ws, size_t ws_size,
                              hipStream_t stream){
    const float* z    = (const float*)d_in[0];
    const int*   mask = (const int*)d_in[1];

    char* ws = (char*)d_ws;
    const size_t MB = (size_t)1<<20;
    u16* zn   = (u16*)(ws + 0*MB);      // 16 MB [t][128] bf16
    u16* attn = (u16*)(ws + 16*MB);     // 16 MB [t][128] bf16
    u16* pb   = (u16*)(ws + 32*MB);     // ~231 KB bf16 param block (incl. combined weights)

    prep_params<<<NCONV+129,256,0,stream>>>(
        (const float*)d_in[2],  (const float*)d_in[3],  (const float*)d_in[4],  (const float*)d_in[5],
        (const float*)d_in[6],  (const float*)d_in[7],  (const float*)d_in[8],  (const float*)d_in[9],
        (const float*)d_in[10], (const float*)d_in[11], (const float*)d_in[12], (const float*)d_in[13],
        (const float*)d_in[14], (const float*)d_in[15], (const float*)d_in[16], (const float*)d_in[17],
        pb);
    ln_kernel<<<16384,256,0,stream>>>(z, pb, zn);
    mega_kernel<<<1024,256,0,stream>>>(zn, mask, pb, attn);
    oproj_kernel<<<512,256,0,stream>>>(attn, pb, mask, (float*)d_out);
}